// Round 9
// baseline (2137.361 us; speedup 1.0000x reference)
//
#include <hip/hip_runtime.h>

// SNN forward, xs-path only. Spike layouts zero-halo padded (N,H+2,W+2,T,C), T=40.
// Convs 2-7: MFMA 16x16x32 bf16, EXACT 3-way bf16 weight split.
// conv_t14 (round-6 structure, best measured): BM=128 (2img x 64) x BN=64 x BK=64,
// single 40KB LDS buffer, 2-deep register prefetch rotation (ra/rb/rc), setprio.
// Round-8: __launch_bounds__(256,4) (4 blocks/CU resident) + K-split so every
// conv grid is 1280 blocks (L7: 512).

constexpr int NT = 40;

typedef __attribute__((ext_vector_type(8))) short s16x8;
typedef __attribute__((ext_vector_type(4))) float f32x4;

__device__ __forceinline__ float bf2f(unsigned short u) {
    return __uint_as_float(((unsigned)u) << 16);
}

__device__ __forceinline__ void wg_barrier() {
    __builtin_amdgcn_sched_barrier(0);
    __builtin_amdgcn_s_barrier();
    __builtin_amdgcn_sched_barrier(0);
}

// ---------------- weight transpose for conv1 ----------------
__global__ __launch_bounds__(256) void transpose_w(
    const float* __restrict__ w, float* __restrict__ wt, int CO, int R)
{
    __shared__ float tile[32][33];
    const int r0 = blockIdx.x * 32, c0 = blockIdx.y * 32;
    const int tx = threadIdx.x % 32, ty = threadIdx.x / 32;
#pragma unroll
    for (int k = 0; k < 4; k++) {
        const int co = c0 + ty + k * 8, r = r0 + tx;
        if (co < CO && r < R) tile[ty + k * 8][tx] = w[(size_t)co * R + r];
    }
    __syncthreads();
#pragma unroll
    for (int k = 0; k < 4; k++) {
        const int r = r0 + ty + k * 8, co = c0 + tx;
        if (r < R && co < CO) wt[(size_t)r * CO + co] = tile[tx][ty + k * 8];
    }
}

// ---------------- conv1: 3->128 @32x32 pad1, fp32 VALU, dense out ----------------
__global__ __launch_bounds__(320) void conv1_c(
    const float* __restrict__ in, const float* __restrict__ wt,
    const float* __restrict__ bias, float* __restrict__ out)
{
    __shared__ float xs_[27 * NT];
    __shared__ float wl[27 * 128];
    const int sp = blockIdx.x;
    const int ho = sp >> 5, wo = sp & 31;
    const int n = blockIdx.z;
    const int tid = threadIdx.x;
    const int tt = tid >> 5;
    const int cc = tid & 31;

    float4 acc[4];
#pragma unroll
    for (int j = 0; j < 4; j++) {
        const float bv = bias[cc * 4 + j];
        acc[j] = make_float4(bv, bv, bv, bv);
    }
    for (int u = tid; u < 270; u += 320) {
        const int r = u / 10, q = u % 10;
        const int cil = r / 9, k = r % 9;
        const int hi = ho + k / 3 - 1, wi = wo + k % 3 - 1;
        float4 v = make_float4(0.f, 0.f, 0.f, 0.f);
        if ((unsigned)hi < 32u && (unsigned)wi < 32u)
            v = *reinterpret_cast<const float4*>(
                in + ((size_t)((n * 3 + cil) * 1024 + hi * 32 + wi)) * NT + q * 4);
        *reinterpret_cast<float4*>(&xs_[r * NT + q * 4]) = v;
    }
    for (int u = tid; u < 864; u += 320) {
        const int r = u >> 5, j = u & 31;
        *reinterpret_cast<float4*>(&wl[r * 128 + j * 4]) =
            *reinterpret_cast<const float4*>(wt + r * 128 + j * 4);
    }
    __syncthreads();
#pragma unroll
    for (int r = 0; r < 27; ++r) {
        const float4 xv = *reinterpret_cast<const float4*>(&xs_[r * NT + tt * 4]);
        const float4 wv = *reinterpret_cast<const float4*>(&wl[r * 128 + cc * 4]);
        acc[0].x = fmaf(xv.x, wv.x, acc[0].x); acc[0].y = fmaf(xv.y, wv.x, acc[0].y);
        acc[0].z = fmaf(xv.z, wv.x, acc[0].z); acc[0].w = fmaf(xv.w, wv.x, acc[0].w);
        acc[1].x = fmaf(xv.x, wv.y, acc[1].x); acc[1].y = fmaf(xv.y, wv.y, acc[1].y);
        acc[1].z = fmaf(xv.z, wv.y, acc[1].z); acc[1].w = fmaf(xv.w, wv.y, acc[1].w);
        acc[2].x = fmaf(xv.x, wv.z, acc[2].x); acc[2].y = fmaf(xv.y, wv.z, acc[2].y);
        acc[2].z = fmaf(xv.z, wv.z, acc[2].z); acc[2].w = fmaf(xv.w, wv.z, acc[2].w);
        acc[3].x = fmaf(xv.x, wv.w, acc[3].x); acc[3].y = fmaf(xv.y, wv.w, acc[3].y);
        acc[3].z = fmaf(xv.z, wv.w, acc[3].z); acc[3].w = fmaf(xv.w, wv.w, acc[3].w);
    }
    const size_t base = (size_t)(n * 1024 + sp) * (NT * 128);
#pragma unroll
    for (int j = 0; j < 4; j++) {
        const int cb = cc * 4 + j;
        out[base + (tt * 4 + 0) * 128 + cb] = acc[j].x;
        out[base + (tt * 4 + 1) * 128 + cb] = acc[j].y;
        out[base + (tt * 4 + 2) * 128 + cb] = acc[j].z;
        out[base + (tt * 4 + 3) * 128 + cb] = acc[j].w;
    }
}

// ---------------- exact 3-way bf16 split: w[CO][CIN*9] -> {hi,mid,lo}[9][CO][CIN] ----------------
__global__ void split_w(const float* __restrict__ w,
                        unsigned short* __restrict__ hi, unsigned short* __restrict__ mid,
                        unsigned short* __restrict__ lo, int CO, int CIN_)
{
    const int idx = blockIdx.x * blockDim.x + threadIdx.x;
    if (idx >= CO * CIN_) return;
    const int co = idx / CIN_, ci = idx % CIN_;
    const float* src = w + ((size_t)co * CIN_ + ci) * 9;
#pragma unroll
    for (int k = 0; k < 9; ++k) {
        const float f = src[k];
        const unsigned u = __float_as_uint(f);
        const float fh = __uint_as_float(u & 0xFFFF0000u);
        const float r1 = f - fh;
        const unsigned u1 = __float_as_uint(r1);
        const float fm = __uint_as_float(u1 & 0xFFFF0000u);
        const float r2 = r1 - fm;
        const unsigned u2 = __float_as_uint(r2);
        const size_t dst = ((size_t)k * CO + co) * CIN_ + ci;
        hi[dst] = (unsigned short)(u >> 16);
        mid[dst] = (unsigned short)(u1 >> 16);
        lo[dst] = (unsigned short)(u2 >> 16);
    }
}

// ---------------- 2-deep prefetch MFMA conv on padded spikes ----------------
template<int CIN_SEG, int COUT, int HP, int WP, int NSPLIT>
__global__ __launch_bounds__(256, 4) void conv_t14(
    const unsigned short* __restrict__ spk,
    const unsigned short* __restrict__ wlo, const unsigned short* __restrict__ wmid,
    const unsigned short* __restrict__ whi,
    const float* __restrict__ bias, float* __restrict__ out)
{
    constexpr int CIN = CIN_SEG * NSPLIT;
    constexpr int HO = HP - 2, WO = WP - 2;
    constexpr int MROW = WO * NT;
    constexpr int MTILES = (MROW + 63) / 64;
    constexpr bool RAGGED = (MROW % 64) != 0;
    constexpr int KC = CIN_SEG / 64;
    constexpr int NCHUNK = 9 * KC;
    static_assert(NCHUNK % 3 == 0, "rotation unrolled by 3");
    constexpr int NX = HO * MTILES;
    constexpr int NY = COUT / 64;
    constexpr int NB = NX * NY * NSPLIT;
    static_assert(NB % 8 == 0, "grid must divide across 8 XCDs");
    constexpr int Q = NB / 8;
    constexpr size_t SLAB = (size_t)2 * HO * WO * NT * COUT;

    __shared__ unsigned short smem[20480];   // A[128][64] + B[3][64][64] = 40 KiB

    // XCD-chunked swizzle: x fastest, then y, then split -> each XCD owns
    // (y,split) pairs: B panel + K-slice of A stay L2-resident.
    const int g = blockIdx.x;
    const int orig = (g & 7) * Q + (g >> 3);
    const int x = orig % NX;
    const int y = (orig / NX) % NY;
    const int split = orig / (NX * NY);
    const int ho = x / MTILES;
    const int m0 = (x % MTILES) * 64;
    const int co0 = y * 64;

    const int tid = threadIdx.x;
    const int lane = tid & 63;
    const int wv = tid >> 6;
    const int wm = wv >> 1, wn = wv & 1;
    const int lr = lane >> 4, lc = lane & 15;
    const int rlane = lane >> 3, blane = lane & 7;
    const int swz = ((blane ^ rlane) << 3);

    // per-slot constants (slot = wv*10 + s; 0-15: A img rows, 16-39: B 3 splits)
    int lofs[10]; int arow[10]; int gstat[10]; const unsigned short* wbase[10]; bool isA[10];
#pragma unroll
    for (int s = 0; s < 10; ++s) {
        const int slot = wv * 10 + s;
        if (slot < 16) {
            const int img = slot >> 3, r0 = (slot & 7) << 3;
            isA[s] = true;
            arow[s] = m0 + r0 + rlane;
            lofs[s] = (img * 64 + r0 + rlane) * 64 + swz;
            gstat[s] = (int)((img * HP * WP * NT + arow[s]) * CIN + blane * 8);
            wbase[s] = spk;
        } else {
            const int si = slot - 16;
            const int sp_ = si >> 3, r0 = (si & 7) << 3;
            isA[s] = false;
            arow[s] = 0;
            lofs[s] = 8192 + (sp_ * 64 + r0 + rlane) * 64 + swz;
            gstat[s] = (int)((co0 + r0 + rlane) * CIN + blane * 8);
            wbase[s] = (sp_ == 0) ? wlo : ((sp_ == 1) ? wmid : whi);
        }
    }

    f32x4 acc[2][2][2];
#pragma unroll
    for (int img = 0; img < 2; ++img)
#pragma unroll
        for (int mf = 0; mf < 2; ++mf)
#pragma unroll
            for (int nf = 0; nf < 2; ++nf) {
                const float bv = (NSPLIT == 1 || split == 0)
                    ? bias[co0 + wn * 32 + nf * 16 + lc] : 0.f;
                acc[img][mf][nf] = {bv, bv, bv, bv};
            }

    auto loadchunk = [&](s16x8 (&r)[10], int c) {
        const int kh = c / (3 * KC);
        const int rem = c - kh * 3 * KC;
        const int kw = rem / KC;
        const int kc = rem - kw * KC;
        const int khw = kh * 3 + kw;
        const int ci0 = split * CIN_SEG + kc * 64;
        const size_t aoff = ((size_t)(ho + kh) * WP * NT + (size_t)kw * NT) * CIN + ci0;
        const size_t boff = (size_t)khw * COUT * CIN + ci0;
#pragma unroll
        for (int s = 0; s < 10; ++s) {
            if (isA[s]) {
                if (!RAGGED) {
                    r[s] = *(const s16x8*)(spk + aoff + (size_t)gstat[s]);
                } else {
                    s16x8 v = {0, 0, 0, 0, 0, 0, 0, 0};
                    if (arow[s] < MROW)
                        v = *(const s16x8*)(spk + aoff + (size_t)gstat[s]);
                    r[s] = v;
                }
            } else {
                r[s] = *(const s16x8*)(wbase[s] + boff + (size_t)gstat[s]);
            }
        }
    };

    auto writechunk = [&](s16x8 (&r)[10]) {
#pragma unroll
        for (int s = 0; s < 10; ++s)
            *(s16x8*)&smem[lofs[s]] = r[s];
    };

    auto compute = [&]() {
        __builtin_amdgcn_s_setprio(1);
#pragma unroll
        for (int kcs = 0; kcs < 2; ++kcs) {
            const int cswz = (((kcs * 4 + lr) ^ (lc & 7)) << 3);
            s16x8 af[2][2];
#pragma unroll
            for (int img = 0; img < 2; ++img)
#pragma unroll
                for (int mf = 0; mf < 2; ++mf)
                    af[img][mf] = *(const s16x8*)&smem[(img * 64 + wm * 32 + mf * 16 + lc) * 64 + cswz];
#pragma unroll
            for (int s = 0; s < 3; ++s)
#pragma unroll
                for (int nf = 0; nf < 2; ++nf) {
                    const s16x8 bq = *(const s16x8*)&smem[8192 + s * 4096 + (wn * 32 + nf * 16 + lc) * 64 + cswz];
#pragma unroll
                    for (int img = 0; img < 2; ++img)
#pragma unroll
                        for (int mf = 0; mf < 2; ++mf)
                            acc[img][mf][nf] = __builtin_amdgcn_mfma_f32_16x16x32_bf16(
                                af[img][mf], bq, acc[img][mf][nf], 0, 0, 0);
                }
        }
        __builtin_amdgcn_s_setprio(0);
    };

    s16x8 ra[10], rb[10], rc[10];
    loadchunk(ra, 0);
    loadchunk(rb, 1);
#pragma unroll 1
    for (int c = 0; c < NCHUNK; c += 3) {
        writechunk(ra);                      // vmcnt waits only for ra's loads
        if (c + 2 < NCHUNK) loadchunk(rc, c + 2);
        asm volatile("s_waitcnt lgkmcnt(0)" ::: "memory");
        wg_barrier();
        compute();
        wg_barrier();
        writechunk(rb);
        if (c + 3 < NCHUNK) loadchunk(ra, c + 3);
        asm volatile("s_waitcnt lgkmcnt(0)" ::: "memory");
        wg_barrier();
        compute();
        wg_barrier();
        writechunk(rc);
        if (c + 4 < NCHUNK) loadchunk(rb, c + 4);
        asm volatile("s_waitcnt lgkmcnt(0)" ::: "memory");
        wg_barrier();
        compute();
        wg_barrier();
    }

#pragma unroll
    for (int img = 0; img < 2; ++img) {
        float* outp = out + (size_t)split * SLAB + ((size_t)(img * HO + ho) * WO * NT) * COUT;
#pragma unroll
        for (int mf = 0; mf < 2; ++mf) {
            const int mbase = m0 + wm * 32 + mf * 16;
            if (RAGGED && mbase >= MROW) continue;
#pragma unroll
            for (int nf = 0; nf < 2; ++nf) {
                const int col = co0 + wn * 32 + nf * 16 + lc;
#pragma unroll
                for (int j = 0; j < 4; ++j) {
                    const int m = mbase + lr * 4 + j;
                    outp[(size_t)m * COUT + col] = acc[img][mf][nf][j];
                }
            }
        }
    }
}

// ---------------- IF scan over NSLAB K-split slabs, reg-buffered; halo-zero fused ----------------
template<int NSLAB>
__global__ void if_ci(const float* __restrict__ in, unsigned short* __restrict__ spk,
                      const float* __restrict__ thr, int C, int HO, int WO,
                      int HP, int WP, int off, int total, size_t slab,
                      int nmain, int halocells)
{
    if ((int)blockIdx.x >= nmain) {
        const int hb = blockIdx.x - nmain;
        const int n = hb / halocells, cell = hb % halocells;
        int h, w;
        if (cell < WP)          { h = 0;      w = cell; }
        else if (cell < 2 * WP) { h = HP - 1; w = cell - WP; }
        else { const int s = cell - 2 * WP; h = 1 + (s >> 1); w = (s & 1) ? (WP - 1) : 0; }
        unsigned short* p = spk + (((size_t)(n * HP + h) * WP) + w) * (size_t)(NT * C);
        const s16x8 z = {0, 0, 0, 0, 0, 0, 0, 0};
        for (int i = threadIdx.x * 8; i < NT * C; i += blockDim.x * 8)
            *(s16x8*)(p + i) = z;
        return;
    }
    const int idx = blockIdx.x * blockDim.x + threadIdx.x;
    if (idx >= total) return;
    const int c = idx % C;
    const int sp = idx / C;
    const int wo = sp % WO;
    const int ho = (sp / WO) % HO;
    const int n = sp / (WO * HO);
    const float th = thr[c];
    const size_t ib = (size_t)sp * NT * C + c;
    const size_t ob = (((size_t)(n * HP + ho + off) * WP) + wo + off) * NT * C + c;
    float xs[NT];
#pragma unroll
    for (int t = 0; t < NT; ++t) {
        float x = in[ib + (size_t)t * C];
#pragma unroll
        for (int s = 1; s < NSLAB; ++s) x += in[ib + (size_t)s * slab + (size_t)t * C];
        xs[t] = x;
    }
    float v = 0.f;
#pragma unroll
    for (int t = 0; t < NT; ++t) {
        v += xs[t];
        const float s = (v >= th) ? 1.f : 0.f;
        v -= s * th;
        spk[ob + (size_t)t * C] = (s != 0.f) ? (unsigned short)0x3F80 : (unsigned short)0;
    }
}

// ---------------- pool 2x2 + IF, bf16 spikes in -> out; extra blocks zero halo ----------------
__global__ void pool_ci(const unsigned short* __restrict__ in, unsigned short* __restrict__ out,
                        const float* __restrict__ thr, int C, int HO, int WO,
                        int IHP, int IWP, int offi, int OHP, int OWP, int offo,
                        int total, int nmain, int halocells)
{
    if ((int)blockIdx.x >= nmain) {
        const int hb = blockIdx.x - nmain;
        const int n = hb / halocells, cell = hb % halocells;
        int h, w;
        if (cell < OWP)          { h = 0;       w = cell; }
        else if (cell < 2 * OWP) { h = OHP - 1; w = cell - OWP; }
        else { const int s = cell - 2 * OWP; h = 1 + (s >> 1); w = (s & 1) ? (OWP - 1) : 0; }
        unsigned short* p = out + (((size_t)(n * OHP + h) * OWP) + w) * (size_t)(NT * C);
        const s16x8 z = {0, 0, 0, 0, 0, 0, 0, 0};
        for (int i = threadIdx.x * 8; i < NT * C; i += blockDim.x * 8)
            *(s16x8*)(p + i) = z;
        return;
    }
    const int idx = blockIdx.x * blockDim.x + threadIdx.x;
    if (idx >= total) return;
    const int c = idx % C;
    const int sp = idx / C;
    const int wo = sp % WO;
    const int ho = (sp / WO) % HO;
    const int n = sp / (WO * HO);
    const float th = thr[c];
    const size_t i00 = (((size_t)(n * IHP + 2 * ho + offi) * IWP) + 2 * wo + offi) * NT * C + c;
    const size_t dW = (size_t)NT * C, dH = (size_t)IWP * NT * C;
    const size_t ob = (((size_t)(n * OHP + ho + offo) * OWP) + wo + offo) * NT * C + c;
    float v = 0.f;
#pragma unroll
    for (int t = 0; t < NT; ++t) {
        const size_t o = (size_t)t * C;
        const float a = bf2f(in[i00 + o]) + bf2f(in[i00 + dW + o]) +
                        bf2f(in[i00 + dH + o]) + bf2f(in[i00 + dH + dW + o]);
        v += a * 0.25f;
        const float s = (v >= th) ? 1.f : 0.f;
        v -= s * th;
        out[ob + o] = (s != 0.f) ? (unsigned short)0x3F80 : (unsigned short)0;
    }
}

// ---------------- classifier: bf16 spikes (N,T,1024) ----------------
__global__ __launch_bounds__(1024) void classifier_ci(
    const unsigned short* __restrict__ s, const float* __restrict__ wc,
    const float* __restrict__ bc, float* __restrict__ out)
{
    __shared__ float cnt[2][1024];
    const int c = threadIdx.x;
    for (int n = 0; n < 2; n++) {
        float sum = 0.f;
#pragma unroll
        for (int t = 0; t < NT; ++t) sum += bf2f(s[(size_t)(n * NT + t) * 1024 + c]);
        cnt[n][c] = sum;
    }
    __syncthreads();
    if (threadIdx.x < 20) {
        const int n = threadIdx.x / 10, o = threadIdx.x % 10;
        float a = 0.f;
        for (int k = 0; k < 1024; k++) a += cnt[n][k] * wc[o * 1024 + k];
        out[n * 10 + o] = a * (1.f / 40.f) + bc[o];
    }
}

extern "C" void kernel_launch(void* const* d_in, const int* in_sizes, int n_in,
                              void* d_out, int out_size, void* d_ws, size_t ws_size,
                              hipStream_t stream)
{
    const float* x   = (const float*)d_in[0];
    const float* w1  = (const float*)d_in[1];  const float* b1 = (const float*)d_in[2];
    const float* w2  = (const float*)d_in[3];  const float* b2 = (const float*)d_in[4];
    const float* w3  = (const float*)d_in[5];  const float* b3 = (const float*)d_in[6];
    const float* w4  = (const float*)d_in[7];  const float* b4 = (const float*)d_in[8];
    const float* w5  = (const float*)d_in[9];  const float* b5 = (const float*)d_in[10];
    const float* w6  = (const float*)d_in[11]; const float* b6 = (const float*)d_in[12];
    const float* w7  = (const float*)d_in[13]; const float* b7 = (const float*)d_in[14];
    const float* wc  = (const float*)d_in[15]; const float* bc = (const float*)d_in[16];
    const float* thr1 = (const float*)d_in[17];
    const float* thr2 = (const float*)d_in[18];
    const float* p1   = (const float*)d_in[19];
    const float* thr3 = (const float*)d_in[20];
    const float* thr4 = (const float*)d_in[21];
    const float* p2   = (const float*)d_in[22];
    const float* thr5 = (const float*)d_in[23];
    const float* thr6 = (const float*)d_in[24];
    const float* p3   = (const float*)d_in[25];
    const float* thr7 = (const float*)d_in[26];
    const float* p4   = (const float*)d_in[27];

    char* W0 = (char*)d_ws;
    float* OUT = (float*)W0;                                              // 44 MiB fp32 (+slabs)
    unsigned short* WH   = (unsigned short*)(W0 + (44ull << 20));         // 9 MiB
    unsigned short* WMID = (unsigned short*)(W0 + (53ull << 20));         // 9 MiB
    unsigned short* WLO  = (unsigned short*)(W0 + (62ull << 20));         // 9 MiB
    unsigned short* R1   = (unsigned short*)(W0 + (71ull << 20));         // 24 MiB: S1,S3,S5
    unsigned short* R2   = (unsigned short*)(W0 + (95ull << 20));         // 7 MiB:  S2,S4,S6
    unsigned short* R3   = (unsigned short*)(W0 + (102ull << 20));        // 20 MiB: U2,U4,U6,S7,P4
    float* WT1 = (float*)(W0 + (122ull << 20));
    unsigned short* S1 = R1, *S3 = R1, *S5 = R1;
    unsigned short* S2 = R2, *S4 = R2, *S6 = R2;
    unsigned short* U2 = R3, *U4 = R3, *U6 = R3;
    unsigned short* S7 = R3;
    unsigned short* P4 = (unsigned short*)((char*)R3 + (2ull << 20));
    float* O = (float*)d_out;

    // L1: conv1 fp32 -> OUT; IF -> S1 (padded 34x34)
    transpose_w<<<dim3(1, 4), 256, 0, stream>>>(w1, WT1, 128, 27);
    conv1_c<<<dim3(1024, 1, 2), 320, 0, stream>>>(x, WT1, b1, OUT);
    if_ci<1><<<1024 + 264, 256, 0, stream>>>(OUT, S1, thr1, 128, 32, 32, 34, 34, 1,
                                             262144, 0, 1024, 132);

    // L2: NSPLIT=1, 1280 blocks
    split_w<<<64, 256, 0, stream>>>(w2, WH, WMID, WLO, 128, 128);
    conv_t14<128, 128, 34, 34, 1><<<1280, 256, 0, stream>>>(S1, WLO, WMID, WH, b2, OUT);
    if_ci<1><<<1024, 256, 0, stream>>>(OUT, U2, thr2, 128, 32, 32, 32, 32, 0,
                                       262144, 0, 1024, 0);
    pool_ci<<<256 + 136, 256, 0, stream>>>(U2, S2, p1, 128, 16, 16, 32, 32, 0,
                                           18, 18, 1, 65536, 256, 68);

    // L3: K-split x2 -> 1280 blocks; slab = 2*16*16*40*256
    split_w<<<128, 256, 0, stream>>>(w3, WH, WMID, WLO, 256, 128);
    conv_t14<64, 256, 18, 18, 2><<<1280, 256, 0, stream>>>(S2, WLO, WMID, WH, b3, OUT);
    if_ci<2><<<512 + 136, 256, 0, stream>>>(OUT, S3, thr3, 256, 16, 16, 18, 18, 1,
                                            131072, 5242880, 512, 68);

    // L4: K-split x2 -> 1280 blocks
    split_w<<<256, 256, 0, stream>>>(w4, WH, WMID, WLO, 256, 256);
    conv_t14<128, 256, 18, 18, 2><<<1280, 256, 0, stream>>>(S3, WLO, WMID, WH, b4, OUT);
    if_ci<2><<<512, 256, 0, stream>>>(OUT, U4, thr4, 256, 16, 16, 16, 16, 0,
                                      131072, 5242880, 512, 0);
    pool_ci<<<128 + 72, 256, 0, stream>>>(U4, S4, p2, 256, 8, 8, 16, 16, 0,
                                          10, 10, 1, 32768, 128, 36);

    // L5: K-split x4 -> 1280 blocks; slab = 2*8*8*40*512
    split_w<<<512, 256, 0, stream>>>(w5, WH, WMID, WLO, 512, 256);
    conv_t14<64, 512, 10, 10, 4><<<1280, 256, 0, stream>>>(S4, WLO, WMID, WH, b5, OUT);
    if_ci<4><<<256 + 72, 256, 0, stream>>>(OUT, S5, thr5, 512, 8, 8, 10, 10, 1,
                                           65536, 2621440, 256, 36);

    // L6: K-split x4 -> 1280 blocks
    split_w<<<1024, 256, 0, stream>>>(w6, WH, WMID, WLO, 512, 512);
    conv_t14<128, 512, 10, 10, 4><<<1280, 256, 0, stream>>>(S5, WLO, WMID, WH, b6, OUT);
    if_ci<4><<<256, 256, 0, stream>>>(OUT, U6, thr6, 512, 8, 8, 8, 8, 0,
                                      65536, 2621440, 256, 0);
    pool_ci<<<64, 256, 0, stream>>>(U6, S6, p3, 512, 4, 4, 8, 8, 0, 4, 4, 0,
                                    16384, 64, 0);

    // L7: K-split x8 -> 512 blocks; if_ci sums 8 slabs -> S7 dense 2x2
    split_w<<<2048, 256, 0, stream>>>(w7, WH, WMID, WLO, 1024, 512);
    conv_t14<64, 1024, 4, 4, 8><<<512, 256, 0, stream>>>(S6, WLO, WMID, WH, b7, OUT);
    if_ci<8><<<32, 256, 0, stream>>>(OUT, S7, thr7, 1024, 2, 2, 2, 2, 0,
                                     8192, 327680, 32, 0);
    pool_ci<<<8, 256, 0, stream>>>(S7, P4, p4, 1024, 1, 1, 2, 2, 0, 1, 1, 0,
                                   2048, 8, 0);

    // classifier
    classifier_ci<<<1, 1024, 0, stream>>>(P4, wc, bc, O);
}

// Round 10
// 579.081 us; speedup vs baseline: 3.6910x; 3.6910x over previous
//
#include <hip/hip_runtime.h>

// SNN forward, xs-path only. Spike layouts zero-halo padded (N,H+2,W+2,T,C), T=40.
// Convs 2-7: MFMA 16x16x32 bf16, EXACT 3-way bf16 weight split.
// conv_db: BM=128 (2img x 64) x BN=64 x BK=64, DOUBLE-buffered LDS (2x40KB),
// ONE barrier per chunk (ds_write next-buf overlaps MFMA on cur-buf),
// 2 register staging sets, setprio on MFMA cluster, launch_bounds(256,2).

constexpr int NT = 40;

typedef __attribute__((ext_vector_type(8))) short s16x8;
typedef __attribute__((ext_vector_type(4))) float f32x4;

__device__ __forceinline__ float bf2f(unsigned short u) {
    return __uint_as_float(((unsigned)u) << 16);
}

__device__ __forceinline__ void wg_barrier() {
    __builtin_amdgcn_sched_barrier(0);
    __builtin_amdgcn_s_barrier();
    __builtin_amdgcn_sched_barrier(0);
}

// ---------------- weight transpose for conv1 ----------------
__global__ __launch_bounds__(256) void transpose_w(
    const float* __restrict__ w, float* __restrict__ wt, int CO, int R)
{
    __shared__ float tile[32][33];
    const int r0 = blockIdx.x * 32, c0 = blockIdx.y * 32;
    const int tx = threadIdx.x % 32, ty = threadIdx.x / 32;
#pragma unroll
    for (int k = 0; k < 4; k++) {
        const int co = c0 + ty + k * 8, r = r0 + tx;
        if (co < CO && r < R) tile[ty + k * 8][tx] = w[(size_t)co * R + r];
    }
    __syncthreads();
#pragma unroll
    for (int k = 0; k < 4; k++) {
        const int r = r0 + ty + k * 8, co = c0 + tx;
        if (r < R && co < CO) wt[(size_t)r * CO + co] = tile[tx][ty + k * 8];
    }
}

// ---------------- conv1: 3->128 @32x32 pad1, fp32 VALU, dense out ----------------
__global__ __launch_bounds__(320) void conv1_c(
    const float* __restrict__ in, const float* __restrict__ wt,
    const float* __restrict__ bias, float* __restrict__ out)
{
    __shared__ float xs_[27 * NT];
    __shared__ float wl[27 * 128];
    const int sp = blockIdx.x;
    const int ho = sp >> 5, wo = sp & 31;
    const int n = blockIdx.z;
    const int tid = threadIdx.x;
    const int tt = tid >> 5;
    const int cc = tid & 31;

    float4 acc[4];
#pragma unroll
    for (int j = 0; j < 4; j++) {
        const float bv = bias[cc * 4 + j];
        acc[j] = make_float4(bv, bv, bv, bv);
    }
    for (int u = tid; u < 270; u += 320) {
        const int r = u / 10, q = u % 10;
        const int cil = r / 9, k = r % 9;
        const int hi = ho + k / 3 - 1, wi = wo + k % 3 - 1;
        float4 v = make_float4(0.f, 0.f, 0.f, 0.f);
        if ((unsigned)hi < 32u && (unsigned)wi < 32u)
            v = *reinterpret_cast<const float4*>(
                in + ((size_t)((n * 3 + cil) * 1024 + hi * 32 + wi)) * NT + q * 4);
        *reinterpret_cast<float4*>(&xs_[r * NT + q * 4]) = v;
    }
    for (int u = tid; u < 864; u += 320) {
        const int r = u >> 5, j = u & 31;
        *reinterpret_cast<float4*>(&wl[r * 128 + j * 4]) =
            *reinterpret_cast<const float4*>(wt + r * 128 + j * 4);
    }
    __syncthreads();
#pragma unroll
    for (int r = 0; r < 27; ++r) {
        const float4 xv = *reinterpret_cast<const float4*>(&xs_[r * NT + tt * 4]);
        const float4 wv = *reinterpret_cast<const float4*>(&wl[r * 128 + cc * 4]);
        acc[0].x = fmaf(xv.x, wv.x, acc[0].x); acc[0].y = fmaf(xv.y, wv.x, acc[0].y);
        acc[0].z = fmaf(xv.z, wv.x, acc[0].z); acc[0].w = fmaf(xv.w, wv.x, acc[0].w);
        acc[1].x = fmaf(xv.x, wv.y, acc[1].x); acc[1].y = fmaf(xv.y, wv.y, acc[1].y);
        acc[1].z = fmaf(xv.z, wv.y, acc[1].z); acc[1].w = fmaf(xv.w, wv.y, acc[1].w);
        acc[2].x = fmaf(xv.x, wv.z, acc[2].x); acc[2].y = fmaf(xv.y, wv.z, acc[2].y);
        acc[2].z = fmaf(xv.z, wv.z, acc[2].z); acc[2].w = fmaf(xv.w, wv.z, acc[2].w);
        acc[3].x = fmaf(xv.x, wv.w, acc[3].x); acc[3].y = fmaf(xv.y, wv.w, acc[3].y);
        acc[3].z = fmaf(xv.z, wv.w, acc[3].z); acc[3].w = fmaf(xv.w, wv.w, acc[3].w);
    }
    const size_t base = (size_t)(n * 1024 + sp) * (NT * 128);
#pragma unroll
    for (int j = 0; j < 4; j++) {
        const int cb = cc * 4 + j;
        out[base + (tt * 4 + 0) * 128 + cb] = acc[j].x;
        out[base + (tt * 4 + 1) * 128 + cb] = acc[j].y;
        out[base + (tt * 4 + 2) * 128 + cb] = acc[j].z;
        out[base + (tt * 4 + 3) * 128 + cb] = acc[j].w;
    }
}

// ---------------- exact 3-way bf16 split: w[CO][CIN*9] -> {hi,mid,lo}[9][CO][CIN] ----------------
__global__ void split_w(const float* __restrict__ w,
                        unsigned short* __restrict__ hi, unsigned short* __restrict__ mid,
                        unsigned short* __restrict__ lo, int CO, int CIN_)
{
    const int idx = blockIdx.x * blockDim.x + threadIdx.x;
    if (idx >= CO * CIN_) return;
    const int co = idx / CIN_, ci = idx % CIN_;
    const float* src = w + ((size_t)co * CIN_ + ci) * 9;
#pragma unroll
    for (int k = 0; k < 9; ++k) {
        const float f = src[k];
        const unsigned u = __float_as_uint(f);
        const float fh = __uint_as_float(u & 0xFFFF0000u);
        const float r1 = f - fh;
        const unsigned u1 = __float_as_uint(r1);
        const float fm = __uint_as_float(u1 & 0xFFFF0000u);
        const float r2 = r1 - fm;
        const unsigned u2 = __float_as_uint(r2);
        const size_t dst = ((size_t)k * CO + co) * CIN_ + ci;
        hi[dst] = (unsigned short)(u >> 16);
        mid[dst] = (unsigned short)(u1 >> 16);
        lo[dst] = (unsigned short)(u2 >> 16);
    }
}

// ---------------- double-buffered single-barrier MFMA conv on padded spikes ----------------
template<int CIN_SEG, int COUT, int HP, int WP, int NSPLIT>
__global__ __launch_bounds__(256, 2) void conv_db(
    const unsigned short* __restrict__ spk,
    const unsigned short* __restrict__ wlo, const unsigned short* __restrict__ wmid,
    const unsigned short* __restrict__ whi,
    const float* __restrict__ bias, float* __restrict__ out)
{
    constexpr int CIN = CIN_SEG * NSPLIT;
    constexpr int HO = HP - 2, WO = WP - 2;
    constexpr int MROW = WO * NT;
    constexpr int MTILES = (MROW + 63) / 64;
    constexpr bool RAGGED = (MROW % 64) != 0;
    constexpr int KC = CIN_SEG / 64;
    constexpr int NCHUNK = 9 * KC;
    constexpr int NX = HO * MTILES;
    constexpr int NY = COUT / 64;
    constexpr int NB = NX * NY * NSPLIT;
    static_assert(NB % 8 == 0, "grid must divide across 8 XCDs");
    constexpr int Q = NB / 8;
    constexpr size_t SLAB = (size_t)2 * HO * WO * NT * COUT;

    __shared__ unsigned short smem[2][20480];   // 2 x (A[128][64] + B[3][64][64]) = 80 KiB

    // XCD-chunked swizzle: x fastest, then y, then split -> each XCD owns
    // (y,split) pairs: B panel + K-slice of A stay L2-resident.
    const int g = blockIdx.x;
    const int orig = (g & 7) * Q + (g >> 3);
    const int x = orig % NX;
    const int y = (orig / NX) % NY;
    const int split = orig / (NX * NY);
    const int ho = x / MTILES;
    const int m0 = (x % MTILES) * 64;
    const int co0 = y * 64;

    const int tid = threadIdx.x;
    const int lane = tid & 63;
    const int wv = tid >> 6;
    const int wm = wv >> 1, wn = wv & 1;
    const int lr = lane >> 4, lc = lane & 15;
    const int rlane = lane >> 3, blane = lane & 7;
    const int swz = ((blane ^ rlane) << 3);

    // per-slot constants (slot = wv*10 + s; 0-15: A img rows, 16-39: B 3 splits)
    int lofs[10]; int arow[10]; int gstat[10]; const unsigned short* wbase[10]; bool isA[10];
#pragma unroll
    for (int s = 0; s < 10; ++s) {
        const int slot = wv * 10 + s;
        if (slot < 16) {
            const int img = slot >> 3, r0 = (slot & 7) << 3;
            isA[s] = true;
            arow[s] = m0 + r0 + rlane;
            lofs[s] = (img * 64 + r0 + rlane) * 64 + swz;
            gstat[s] = (int)((img * HP * WP * NT + arow[s]) * CIN + blane * 8);
            wbase[s] = spk;
        } else {
            const int si = slot - 16;
            const int sp_ = si >> 3, r0 = (si & 7) << 3;
            isA[s] = false;
            arow[s] = 0;
            lofs[s] = 8192 + (sp_ * 64 + r0 + rlane) * 64 + swz;
            gstat[s] = (int)((co0 + r0 + rlane) * CIN + blane * 8);
            wbase[s] = (sp_ == 0) ? wlo : ((sp_ == 1) ? wmid : whi);
        }
    }

    f32x4 acc[2][2][2];
#pragma unroll
    for (int img = 0; img < 2; ++img)
#pragma unroll
        for (int mf = 0; mf < 2; ++mf)
#pragma unroll
            for (int nf = 0; nf < 2; ++nf) {
                const float bv = (NSPLIT == 1 || split == 0)
                    ? bias[co0 + wn * 32 + nf * 16 + lc] : 0.f;
                acc[img][mf][nf] = {bv, bv, bv, bv};
            }

    auto loadchunk = [&](s16x8 (&r)[10], int c) {
        const int kh = c / (3 * KC);
        const int rem = c - kh * 3 * KC;
        const int kw = rem / KC;
        const int kc = rem - kw * KC;
        const int khw = kh * 3 + kw;
        const int ci0 = split * CIN_SEG + kc * 64;
        const size_t aoff = ((size_t)(ho + kh) * WP * NT + (size_t)kw * NT) * CIN + ci0;
        const size_t boff = (size_t)khw * COUT * CIN + ci0;
#pragma unroll
        for (int s = 0; s < 10; ++s) {
            if (isA[s]) {
                if (!RAGGED) {
                    r[s] = *(const s16x8*)(spk + aoff + (size_t)gstat[s]);
                } else {
                    s16x8 v = {0, 0, 0, 0, 0, 0, 0, 0};
                    if (arow[s] < MROW)
                        v = *(const s16x8*)(spk + aoff + (size_t)gstat[s]);
                    r[s] = v;
                }
            } else {
                r[s] = *(const s16x8*)(wbase[s] + boff + (size_t)gstat[s]);
            }
        }
    };

    auto writechunk = [&](s16x8 (&r)[10], unsigned short* base) {
#pragma unroll
        for (int s = 0; s < 10; ++s)
            *(s16x8*)&base[lofs[s]] = r[s];
    };

    auto compute = [&](const unsigned short* sb) {
        __builtin_amdgcn_s_setprio(1);
#pragma unroll
        for (int kcs = 0; kcs < 2; ++kcs) {
            const int cswz = (((kcs * 4 + lr) ^ (lc & 7)) << 3);
            s16x8 af[2][2];
#pragma unroll
            for (int img = 0; img < 2; ++img)
#pragma unroll
                for (int mf = 0; mf < 2; ++mf)
                    af[img][mf] = *(const s16x8*)&sb[(img * 64 + wm * 32 + mf * 16 + lc) * 64 + cswz];
#pragma unroll
            for (int s = 0; s < 3; ++s)
#pragma unroll
                for (int nf = 0; nf < 2; ++nf) {
                    const s16x8 bq = *(const s16x8*)&sb[8192 + s * 4096 + (wn * 32 + nf * 16 + lc) * 64 + cswz];
#pragma unroll
                    for (int img = 0; img < 2; ++img)
#pragma unroll
                        for (int mf = 0; mf < 2; ++mf)
                            acc[img][mf][nf] = __builtin_amdgcn_mfma_f32_16x16x32_bf16(
                                af[img][mf], bq, acc[img][mf][nf], 0, 0, 0);
                }
        }
        __builtin_amdgcn_s_setprio(0);
    };

    // pipeline: chunk parity == LDS buffer index; ONE barrier per chunk.
    s16x8 rE[10], rO[10];
    loadchunk(rE, 0);
    loadchunk(rO, 1);                       // NCHUNK >= 9 always
    writechunk(rE, smem[0]);
    asm volatile("s_waitcnt lgkmcnt(0)" ::: "memory");
    wg_barrier();
#pragma unroll 1
    for (int c = 0; c < NCHUNK; c += 2) {
        if (c + 1 < NCHUNK) writechunk(rO, smem[1]);   // chunk c+1 -> buf1, overlaps compute
        if (c + 2 < NCHUNK) loadchunk(rE, c + 2);
        __builtin_amdgcn_sched_barrier(0);
        compute(smem[0]);                              // chunk c
        asm volatile("s_waitcnt lgkmcnt(0)" ::: "memory");
        wg_barrier();
        if (c + 1 >= NCHUNK) break;
        if (c + 2 < NCHUNK) writechunk(rE, smem[0]);   // chunk c+2 -> buf0
        if (c + 3 < NCHUNK) loadchunk(rO, c + 3);
        __builtin_amdgcn_sched_barrier(0);
        compute(smem[1]);                              // chunk c+1
        asm volatile("s_waitcnt lgkmcnt(0)" ::: "memory");
        wg_barrier();
    }

#pragma unroll
    for (int img = 0; img < 2; ++img) {
        float* outp = out + (size_t)split * SLAB + ((size_t)(img * HO + ho) * WO * NT) * COUT;
#pragma unroll
        for (int mf = 0; mf < 2; ++mf) {
            const int mbase = m0 + wm * 32 + mf * 16;
            if (RAGGED && mbase >= MROW) continue;
#pragma unroll
            for (int nf = 0; nf < 2; ++nf) {
                const int col = co0 + wn * 32 + nf * 16 + lc;
#pragma unroll
                for (int j = 0; j < 4; ++j) {
                    const int m = mbase + lr * 4 + j;
                    outp[(size_t)m * COUT + col] = acc[img][mf][nf][j];
                }
            }
        }
    }
}

// ---------------- IF scan over NSLAB K-split slabs, reg-buffered; halo-zero fused ----------------
template<int NSLAB>
__global__ void if_ci(const float* __restrict__ in, unsigned short* __restrict__ spk,
                      const float* __restrict__ thr, int C, int HO, int WO,
                      int HP, int WP, int off, int total, size_t slab,
                      int nmain, int halocells)
{
    if ((int)blockIdx.x >= nmain) {
        const int hb = blockIdx.x - nmain;
        const int n = hb / halocells, cell = hb % halocells;
        int h, w;
        if (cell < WP)          { h = 0;      w = cell; }
        else if (cell < 2 * WP) { h = HP - 1; w = cell - WP; }
        else { const int s = cell - 2 * WP; h = 1 + (s >> 1); w = (s & 1) ? (WP - 1) : 0; }
        unsigned short* p = spk + (((size_t)(n * HP + h) * WP) + w) * (size_t)(NT * C);
        const s16x8 z = {0, 0, 0, 0, 0, 0, 0, 0};
        for (int i = threadIdx.x * 8; i < NT * C; i += blockDim.x * 8)
            *(s16x8*)(p + i) = z;
        return;
    }
    const int idx = blockIdx.x * blockDim.x + threadIdx.x;
    if (idx >= total) return;
    const int c = idx % C;
    const int sp = idx / C;
    const int wo = sp % WO;
    const int ho = (sp / WO) % HO;
    const int n = sp / (WO * HO);
    const float th = thr[c];
    const size_t ib = (size_t)sp * NT * C + c;
    const size_t ob = (((size_t)(n * HP + ho + off) * WP) + wo + off) * NT * C + c;
    float xs[NT];
#pragma unroll
    for (int t = 0; t < NT; ++t) {
        float x = in[ib + (size_t)t * C];
#pragma unroll
        for (int s = 1; s < NSLAB; ++s) x += in[ib + (size_t)s * slab + (size_t)t * C];
        xs[t] = x;
    }
    float v = 0.f;
#pragma unroll
    for (int t = 0; t < NT; ++t) {
        v += xs[t];
        const float s = (v >= th) ? 1.f : 0.f;
        v -= s * th;
        spk[ob + (size_t)t * C] = (s != 0.f) ? (unsigned short)0x3F80 : (unsigned short)0;
    }
}

// ---------------- pool 2x2 + IF, bf16 spikes in -> out; extra blocks zero halo ----------------
__global__ void pool_ci(const unsigned short* __restrict__ in, unsigned short* __restrict__ out,
                        const float* __restrict__ thr, int C, int HO, int WO,
                        int IHP, int IWP, int offi, int OHP, int OWP, int offo,
                        int total, int nmain, int halocells)
{
    if ((int)blockIdx.x >= nmain) {
        const int hb = blockIdx.x - nmain;
        const int n = hb / halocells, cell = hb % halocells;
        int h, w;
        if (cell < OWP)          { h = 0;       w = cell; }
        else if (cell < 2 * OWP) { h = OHP - 1; w = cell - OWP; }
        else { const int s = cell - 2 * OWP; h = 1 + (s >> 1); w = (s & 1) ? (OWP - 1) : 0; }
        unsigned short* p = out + (((size_t)(n * OHP + h) * OWP) + w) * (size_t)(NT * C);
        const s16x8 z = {0, 0, 0, 0, 0, 0, 0, 0};
        for (int i = threadIdx.x * 8; i < NT * C; i += blockDim.x * 8)
            *(s16x8*)(p + i) = z;
        return;
    }
    const int idx = blockIdx.x * blockDim.x + threadIdx.x;
    if (idx >= total) return;
    const int c = idx % C;
    const int sp = idx / C;
    const int wo = sp % WO;
    const int ho = (sp / WO) % HO;
    const int n = sp / (WO * HO);
    const float th = thr[c];
    const size_t i00 = (((size_t)(n * IHP + 2 * ho + offi) * IWP) + 2 * wo + offi) * NT * C + c;
    const size_t dW = (size_t)NT * C, dH = (size_t)IWP * NT * C;
    const size_t ob = (((size_t)(n * OHP + ho + offo) * OWP) + wo + offo) * NT * C + c;
    float v = 0.f;
#pragma unroll
    for (int t = 0; t < NT; ++t) {
        const size_t o = (size_t)t * C;
        const float a = bf2f(in[i00 + o]) + bf2f(in[i00 + dW + o]) +
                        bf2f(in[i00 + dH + o]) + bf2f(in[i00 + dH + dW + o]);
        v += a * 0.25f;
        const float s = (v >= th) ? 1.f : 0.f;
        v -= s * th;
        out[ob + o] = (s != 0.f) ? (unsigned short)0x3F80 : (unsigned short)0;
    }
}

// ---------------- classifier: bf16 spikes (N,T,1024) ----------------
__global__ __launch_bounds__(1024) void classifier_ci(
    const unsigned short* __restrict__ s, const float* __restrict__ wc,
    const float* __restrict__ bc, float* __restrict__ out)
{
    __shared__ float cnt[2][1024];
    const int c = threadIdx.x;
    for (int n = 0; n < 2; n++) {
        float sum = 0.f;
#pragma unroll
        for (int t = 0; t < NT; ++t) sum += bf2f(s[(size_t)(n * NT + t) * 1024 + c]);
        cnt[n][c] = sum;
    }
    __syncthreads();
    if (threadIdx.x < 20) {
        const int n = threadIdx.x / 10, o = threadIdx.x % 10;
        float a = 0.f;
        for (int k = 0; k < 1024; k++) a += cnt[n][k] * wc[o * 1024 + k];
        out[n * 10 + o] = a * (1.f / 40.f) + bc[o];
    }
}

extern "C" void kernel_launch(void* const* d_in, const int* in_sizes, int n_in,
                              void* d_out, int out_size, void* d_ws, size_t ws_size,
                              hipStream_t stream)
{
    const float* x   = (const float*)d_in[0];
    const float* w1  = (const float*)d_in[1];  const float* b1 = (const float*)d_in[2];
    const float* w2  = (const float*)d_in[3];  const float* b2 = (const float*)d_in[4];
    const float* w3  = (const float*)d_in[5];  const float* b3 = (const float*)d_in[6];
    const float* w4  = (const float*)d_in[7];  const float* b4 = (const float*)d_in[8];
    const float* w5  = (const float*)d_in[9];  const float* b5 = (const float*)d_in[10];
    const float* w6  = (const float*)d_in[11]; const float* b6 = (const float*)d_in[12];
    const float* w7  = (const float*)d_in[13]; const float* b7 = (const float*)d_in[14];
    const float* wc  = (const float*)d_in[15]; const float* bc = (const float*)d_in[16];
    const float* thr1 = (const float*)d_in[17];
    const float* thr2 = (const float*)d_in[18];
    const float* p1   = (const float*)d_in[19];
    const float* thr3 = (const float*)d_in[20];
    const float* thr4 = (const float*)d_in[21];
    const float* p2   = (const float*)d_in[22];
    const float* thr5 = (const float*)d_in[23];
    const float* thr6 = (const float*)d_in[24];
    const float* p3   = (const float*)d_in[25];
    const float* thr7 = (const float*)d_in[26];
    const float* p4   = (const float*)d_in[27];

    char* W0 = (char*)d_ws;
    float* OUT = (float*)W0;                                              // 44 MiB fp32 (+slabs)
    unsigned short* WH   = (unsigned short*)(W0 + (44ull << 20));         // 9 MiB
    unsigned short* WMID = (unsigned short*)(W0 + (53ull << 20));         // 9 MiB
    unsigned short* WLO  = (unsigned short*)(W0 + (62ull << 20));         // 9 MiB
    unsigned short* R1   = (unsigned short*)(W0 + (71ull << 20));         // 24 MiB: S1,S3,S5
    unsigned short* R2   = (unsigned short*)(W0 + (95ull << 20));         // 7 MiB:  S2,S4,S6
    unsigned short* R3   = (unsigned short*)(W0 + (102ull << 20));        // 20 MiB: U2,U4,U6,S7,P4
    float* WT1 = (float*)(W0 + (122ull << 20));
    unsigned short* S1 = R1, *S3 = R1, *S5 = R1;
    unsigned short* S2 = R2, *S4 = R2, *S6 = R2;
    unsigned short* U2 = R3, *U4 = R3, *U6 = R3;
    unsigned short* S7 = R3;
    unsigned short* P4 = (unsigned short*)((char*)R3 + (2ull << 20));
    float* O = (float*)d_out;

    // L1: conv1 fp32 -> OUT; IF -> S1 (padded 34x34)
    transpose_w<<<dim3(1, 4), 256, 0, stream>>>(w1, WT1, 128, 27);
    conv1_c<<<dim3(1024, 1, 2), 320, 0, stream>>>(x, WT1, b1, OUT);
    if_ci<1><<<1024 + 264, 256, 0, stream>>>(OUT, S1, thr1, 128, 32, 32, 34, 34, 1,
                                             262144, 0, 1024, 132);

    // L2: 1280 blocks, NCHUNK=18
    split_w<<<64, 256, 0, stream>>>(w2, WH, WMID, WLO, 128, 128);
    conv_db<128, 128, 34, 34, 1><<<1280, 256, 0, stream>>>(S1, WLO, WMID, WH, b2, OUT);
    if_ci<1><<<1024, 256, 0, stream>>>(OUT, U2, thr2, 128, 32, 32, 32, 32, 0,
                                       262144, 0, 1024, 0);
    pool_ci<<<256 + 136, 256, 0, stream>>>(U2, S2, p1, 128, 16, 16, 32, 32, 0,
                                           18, 18, 1, 65536, 256, 68);

    // L3: 640 blocks, NCHUNK=18
    split_w<<<128, 256, 0, stream>>>(w3, WH, WMID, WLO, 256, 128);
    conv_db<128, 256, 18, 18, 1><<<640, 256, 0, stream>>>(S2, WLO, WMID, WH, b3, OUT);
    if_ci<1><<<512 + 136, 256, 0, stream>>>(OUT, S3, thr3, 256, 16, 16, 18, 18, 1,
                                            131072, 0, 512, 68);

    // L4: 640 blocks, NCHUNK=36
    split_w<<<256, 256, 0, stream>>>(w4, WH, WMID, WLO, 256, 256);
    conv_db<256, 256, 18, 18, 1><<<640, 256, 0, stream>>>(S3, WLO, WMID, WH, b4, OUT);
    if_ci<1><<<512, 256, 0, stream>>>(OUT, U4, thr4, 256, 16, 16, 16, 16, 0,
                                      131072, 0, 512, 0);
    pool_ci<<<128 + 72, 256, 0, stream>>>(U4, S4, p2, 256, 8, 8, 16, 16, 0,
                                          10, 10, 1, 32768, 128, 36);

    // L5: K-split x2 -> 640 blocks, NCHUNK=18; if_ci sums 2 slabs
    split_w<<<512, 256, 0, stream>>>(w5, WH, WMID, WLO, 512, 256);
    conv_db<128, 512, 10, 10, 2><<<640, 256, 0, stream>>>(S4, WLO, WMID, WH, b5, OUT);
    if_ci<2><<<256 + 72, 256, 0, stream>>>(OUT, S5, thr5, 512, 8, 8, 10, 10, 1,
                                           65536, 2621440, 256, 36);

    // L6: K-split x2 -> 640 blocks, NCHUNK=36
    split_w<<<1024, 256, 0, stream>>>(w6, WH, WMID, WLO, 512, 512);
    conv_db<256, 512, 10, 10, 2><<<640, 256, 0, stream>>>(S5, WLO, WMID, WH, b6, OUT);
    if_ci<2><<<256, 256, 0, stream>>>(OUT, U6, thr6, 512, 8, 8, 8, 8, 0,
                                      65536, 2621440, 256, 0);
    pool_ci<<<64, 256, 0, stream>>>(U6, S6, p3, 512, 4, 4, 8, 8, 0, 4, 4, 0,
                                    16384, 64, 0);

    // L7: K-split x8 -> 512 blocks, NCHUNK=9; if_ci sums 8 slabs -> S7 dense 2x2
    split_w<<<2048, 256, 0, stream>>>(w7, WH, WMID, WLO, 1024, 512);
    conv_db<64, 1024, 4, 4, 8><<<512, 256, 0, stream>>>(S6, WLO, WMID, WH, b7, OUT);
    if_ci<8><<<32, 256, 0, stream>>>(OUT, S7, thr7, 1024, 2, 2, 2, 2, 0,
                                     8192, 327680, 32, 0);
    pool_ci<<<8, 256, 0, stream>>>(S7, P4, p4, 1024, 1, 1, 2, 2, 0, 1, 1, 0,
                                   2048, 8, 0);

    // classifier
    classifier_ci<<<1, 1024, 0, stream>>>(P4, wc, bc, O);
}